// Round 2
// baseline (193.439 us; speedup 1.0000x reference)
//
#include <hip/hip_runtime.h>

#define N_NODES 50000
#define N_EDGES 600000
#define D 128
#define TILE_N 32
#define SCAN_B 1024
#define N_SCAN_BLOCKS ((N_NODES + SCAN_B - 1) / SCAN_B)   // 49

typedef float f4 __attribute__((ext_vector_type(4)));

// ===========================================================================
// R2 structure: 5 dispatches.
//   memset(cursor+desc) -> hist -> single-kernel scan (decoupled aggregates)
//   -> fill -> fused gather+GEMM tile kernel (A never hits HBM).
//   out = ((h .* segsum(e_h, dst)) @ W^T + b) * norm
// ===========================================================================

__global__ __launch_bounds__(256) void hist_kernel(
    const int* __restrict__ dst, int* __restrict__ cnt)
{
    int e = blockIdx.x * 256 + threadIdx.x;
    if (e < N_EDGES) atomicAdd(&cnt[dst[e]], 1);
}

// ---------------------------------------------------------------------------
// One-kernel exclusive scan over cnt[N_NODES], 49 blocks x 1024.
// Each block: LDS/shuffle block scan, publish aggregate (bit63 = ready) with
// device-scope release; one wave spins until all PREDECESSOR aggregates are
// visible (predecessor-only wait + 49 blocks << capacity => no deadlock),
// reduces them for the block base. Writes offsets[] and cursor[].
// ---------------------------------------------------------------------------
__global__ __launch_bounds__(SCAN_B) void scan_kernel(
    const int* __restrict__ cnt, unsigned long long* __restrict__ desc,
    int* __restrict__ offsets, int* __restrict__ cursor)
{
    const int t  = threadIdx.x;
    const int bx = blockIdx.x;
    const int i  = bx * SCAN_B + t;
    const int v  = (i < N_NODES) ? cnt[i] : 0;

    const int lane = t & 63;
    const int w    = t >> 6;                 // 16 waves
    int incl = v;
#pragma unroll
    for (int s = 1; s < 64; s <<= 1) {
        int u = __shfl_up(incl, s, 64);
        if (lane >= s) incl += u;
    }
    __shared__ int wsum[SCAN_B / 64];
    if (lane == 63) wsum[w] = incl;
    __syncthreads();
    if (t < SCAN_B / 64) {
        int x = wsum[t];
#pragma unroll
        for (int s = 1; s < SCAN_B / 64; s <<= 1) {
            int u = __shfl_up(x, s, SCAN_B / 64);
            if (t >= s) x += u;
        }
        wsum[t] = x;                         // inclusive per-wave prefix
    }
    __syncthreads();
    const int block_total   = wsum[SCAN_B / 64 - 1];
    const int excl_in_block = (w ? wsum[w - 1] : 0) + (incl - v);

    if (t == 0)
        __hip_atomic_store(&desc[bx],
            (unsigned long long)(unsigned)block_total | (1ull << 63),
            __ATOMIC_RELEASE, __HIP_MEMORY_SCOPE_AGENT);

    __shared__ int base_sh;
    if (t < 64) {
        int pred = 0;
        if (t < bx) {                        // bx <= 48 < 64: one wave covers all
            unsigned long long e;
            do {
                e = __hip_atomic_load(&desc[t], __ATOMIC_ACQUIRE,
                                      __HIP_MEMORY_SCOPE_AGENT);
            } while (!(e >> 63));
            pred = (int)(unsigned)e;
        }
#pragma unroll
        for (int s = 32; s > 0; s >>= 1) pred += __shfl_down(pred, s, 64);
        if (t == 0) base_sh = pred;
    }
    __syncthreads();

    const int excl = base_sh + excl_in_block;
    if (i < N_NODES) { offsets[i] = excl; cursor[i] = excl; }
    if (i == N_NODES - 1) offsets[N_NODES] = excl + v;   // == N_EDGES
}

__global__ __launch_bounds__(256) void fill_kernel(
    const int* __restrict__ dst, int* __restrict__ cursor,
    int* __restrict__ edge_ids)
{
    int e = blockIdx.x * 256 + threadIdx.x;
    if (e < N_EDGES) {
        int pos = atomicAdd(&cursor[dst[e]], 1);
        edge_ids[pos] = e;
    }
}

// ---------------------------------------------------------------------------
// Fused gather + GEMM. 32 nodes x 128 cols per 256-thread block.
// Phase 1: stage W swizzled in LDS (64KB). Phase 2: 8 groups of 32 lanes
// gather 4 nodes each (4-deep nt-load pipeline, acc in regs), multiply by
// h[n], write straight into the Al LDS tile (A never touches HBM).
// Phase 3: the proven 4x4-per-thread LDS GEMM + bias/norm epilogue.
// LDS 80KB -> 2 blocks/CU; gather in-flight = 2x8x4 rows = 32KB/CU >= the
// ~11KB BW*latency product, and gather/GEMM phases of neighboring blocks
// overlap on a CU.
// ---------------------------------------------------------------------------
__global__ __launch_bounds__(256, 2) void fused_tile(
    const float* __restrict__ h, const float* __restrict__ e_h,
    const int* __restrict__ offsets, const int* __restrict__ edge_ids,
    const float* __restrict__ norm, const float* __restrict__ W,
    const float* __restrict__ b, float* __restrict__ out)
{
    __shared__ float Wl[D * D];
    __shared__ float Al[TILE_N * D];
    const int tid = threadIdx.x;
    const int n0  = blockIdx.x * TILE_N;

    // ---- stage W (granule-swizzled), loads issued up front ----
    for (int it = 0; it < 16; ++it) {
        int group = it * 256 + tid;
        int c  = group >> 5;
        int kg = group & 31;
        float4 wv = *(const float4*)(W + (size_t)c * D + (kg << 2));
        int g = (kg + c) & 31;
        *(float4*)(Wl + c * D + (g << 2)) = wv;
    }

    // ---- gather phase: group = 32 lanes, 4 nodes sequentially ----
    const int grp  = tid >> 5;
    const int lane = tid & 31;
    const int fo   = lane << 2;

    for (int s = 0; s < 4; ++s) {
        const int nl = grp * 4 + s;
        const int n  = n0 + nl;
        f4 acc = (f4){0.f, 0.f, 0.f, 0.f};
        if (n < N_NODES) {
            const int beg = offsets[n];
            const int end = offsets[n + 1];
            int i = beg;
            const int n4 = beg + ((end - beg) & ~3);
            if (i < n4) {
                int id0 = edge_ids[i + 0];
                int id1 = edge_ids[i + 1];
                int id2 = edge_ids[i + 2];
                int id3 = edge_ids[i + 3];
                i += 4;
                for (; i < n4; i += 4) {
                    int j0 = edge_ids[i + 0];
                    int j1 = edge_ids[i + 1];
                    int j2 = edge_ids[i + 2];
                    int j3 = edge_ids[i + 3];
                    f4 v0 = __builtin_nontemporal_load((const f4*)(e_h + (size_t)id0 * D + fo));
                    f4 v1 = __builtin_nontemporal_load((const f4*)(e_h + (size_t)id1 * D + fo));
                    f4 v2 = __builtin_nontemporal_load((const f4*)(e_h + (size_t)id2 * D + fo));
                    f4 v3 = __builtin_nontemporal_load((const f4*)(e_h + (size_t)id3 * D + fo));
                    acc += (v0 + v1) + (v2 + v3);
                    id0 = j0; id1 = j1; id2 = j2; id3 = j3;
                }
                f4 v0 = __builtin_nontemporal_load((const f4*)(e_h + (size_t)id0 * D + fo));
                f4 v1 = __builtin_nontemporal_load((const f4*)(e_h + (size_t)id1 * D + fo));
                f4 v2 = __builtin_nontemporal_load((const f4*)(e_h + (size_t)id2 * D + fo));
                f4 v3 = __builtin_nontemporal_load((const f4*)(e_h + (size_t)id3 * D + fo));
                acc += (v0 + v1) + (v2 + v3);
            }
            if (i < end) {
                int id = edge_ids[i];
                for (; i < end; ++i) {
                    int nid = (i + 1 < end) ? edge_ids[i + 1] : 0;
                    f4 v = __builtin_nontemporal_load((const f4*)(e_h + (size_t)id * D + fo));
                    acc += v;
                    id = nid;
                }
            }
            f4 hv = *(const f4*)(h + (size_t)n * D + fo);
            acc *= hv;
        }
        *(f4*)(Al + nl * D + fo) = acc;
    }
    __syncthreads();

    // ---- GEMM phase: 4 nodes x 4 cols per thread ----
    const int cg = tid & 31;
    const int ng = tid >> 5;
    float facc[4][4];
#pragma unroll
    for (int i = 0; i < 4; ++i)
#pragma unroll
        for (int j = 0; j < 4; ++j) facc[i][j] = 0.f;

#pragma unroll 4
    for (int kc = 0; kc < 32; ++kc) {
        float4 a[4];
#pragma unroll
        for (int i = 0; i < 4; ++i)
            a[i] = *(const float4*)(Al + (ng * 4 + i) * D + (kc << 2));
        float4 w[4];
#pragma unroll
        for (int j = 0; j < 4; ++j) {
            int c = cg + 32 * j;
            int g = (kc + c) & 31;
            w[j] = *(const float4*)(Wl + c * D + (g << 2));
        }
#pragma unroll
        for (int i = 0; i < 4; ++i)
#pragma unroll
            for (int j = 0; j < 4; ++j)
                facc[i][j] += a[i].x * w[j].x + a[i].y * w[j].y +
                              a[i].z * w[j].z + a[i].w * w[j].w;
    }
    float bias[4];
#pragma unroll
    for (int j = 0; j < 4; ++j) bias[j] = b[cg + 32 * j];
#pragma unroll
    for (int i = 0; i < 4; ++i) {
        int n = n0 + ng * 4 + i;
        if (n >= N_NODES) break;
        float nv = norm[n];
#pragma unroll
        for (int j = 0; j < 4; ++j)
            out[(size_t)n * D + cg + 32 * j] = (facc[i][j] + bias[j]) * nv;
    }
}

// ===========================================================================
// Fallback (tiny ws): float-atomic scatter + fused gemm
// ===========================================================================
__global__ __launch_bounds__(256) void scatter_kernel(
    const float* __restrict__ e_h, const int* __restrict__ dst,
    float* __restrict__ S)
{
    long long idx = (long long)blockIdx.x * 256 + threadIdx.x;
    int edge = (int)(idx >> 5);
    if (edge >= N_EDGES) return;
    int f = ((int)idx & 31) << 2;
    const float4 v = *(const float4*)(e_h + (size_t)edge * D + f);
    float* p = S + (size_t)dst[edge] * D + f;
    atomicAdd(p + 0, v.x);
    atomicAdd(p + 1, v.y);
    atomicAdd(p + 2, v.z);
    atomicAdd(p + 3, v.w);
}

__global__ __launch_bounds__(256, 2) void gemm_kernel(
    const float* __restrict__ h, const float* __restrict__ S,
    const float* __restrict__ norm, const float* __restrict__ W,
    const float* __restrict__ b, float* __restrict__ out)
{
    __shared__ float Wl[D * D];
    __shared__ float Al[TILE_N * D];
    const int tid = threadIdx.x;
    const int n0  = blockIdx.x * TILE_N;

    for (int it = 0; it < 16; ++it) {
        int group = it * 256 + tid;
        int c  = group >> 5;
        int kg = group & 31;
        float4 wv = *(const float4*)(W + (size_t)c * D + (kg << 2));
        int g = (kg + c) & 31;
        *(float4*)(Wl + c * D + (g << 2)) = wv;
    }
    for (int it = 0; it < 4; ++it) {
        int group = it * 256 + tid;
        int nl = group >> 5;
        int f  = (group & 31) << 2;
        int n  = n0 + nl;
        float4 a = make_float4(0.f, 0.f, 0.f, 0.f);
        if (n < N_NODES) {
            float4 hv = *(const float4*)(h + (size_t)n * D + f);
            float4 sv = *(const float4*)(S + (size_t)n * D + f);
            a = make_float4(hv.x * sv.x, hv.y * sv.y, hv.z * sv.z, hv.w * sv.w);
        }
        *(float4*)(Al + nl * D + f) = a;
    }
    __syncthreads();

    const int cg = tid & 31;
    const int ng = tid >> 5;
    float facc[4][4];
#pragma unroll
    for (int i = 0; i < 4; ++i)
#pragma unroll
        for (int j = 0; j < 4; ++j) facc[i][j] = 0.f;

#pragma unroll 4
    for (int kc = 0; kc < 32; ++kc) {
        float4 a[4];
#pragma unroll
        for (int i = 0; i < 4; ++i)
            a[i] = *(const float4*)(Al + (ng * 4 + i) * D + (kc << 2));
        float4 w[4];
#pragma unroll
        for (int j = 0; j < 4; ++j) {
            int c = cg + 32 * j;
            int g = (kc + c) & 31;
            w[j] = *(const float4*)(Wl + c * D + (g << 2));
        }
#pragma unroll
        for (int i = 0; i < 4; ++i)
#pragma unroll
            for (int j = 0; j < 4; ++j)
                facc[i][j] += a[i].x * w[j].x + a[i].y * w[j].y +
                              a[i].z * w[j].z + a[i].w * w[j].w;
    }
    float bias[4];
#pragma unroll
    for (int j = 0; j < 4; ++j) bias[j] = b[cg + 32 * j];
#pragma unroll
    for (int i = 0; i < 4; ++i) {
        int n = n0 + ng * 4 + i;
        if (n >= N_NODES) break;
        float nv = norm[n];
#pragma unroll
        for (int j = 0; j < 4; ++j)
            out[(size_t)n * D + cg + 32 * j] = (facc[i][j] + bias[j]) * nv;
    }
}

// ===========================================================================
extern "C" void kernel_launch(void* const* d_in, const int* in_sizes, int n_in,
                              void* d_out, int out_size, void* d_ws, size_t ws_size,
                              hipStream_t stream) {
    const float* h    = (const float*)d_in[0];
    const float* e_h  = (const float*)d_in[1];
    const float* norm = (const float*)d_in[2];
    const int*   dst  = (const int*)d_in[3];
    const float* W    = (const float*)d_in[4];
    const float* b    = (const float*)d_in[5];
    float* out = (float*)d_out;

    // ws layout: cursor[N] | desc[128 ints = 64 u64] | offsets[N+1] | edge_ids[E]
    const size_t ints_needed = (size_t)N_NODES + 128 + (N_NODES + 1) + N_EDGES;
    const size_t full_bytes  = ints_needed * sizeof(int);

    if (ws_size >= full_bytes) {
        int* cursor   = (int*)d_ws;
        unsigned long long* desc = (unsigned long long*)(cursor + N_NODES);
        int* offsets  = cursor + N_NODES + 128;
        int* edge_ids = offsets + N_NODES + 1;

        // zero counts + scan descriptors in one memset
        hipMemsetAsync(cursor, 0, ((size_t)N_NODES + 128) * sizeof(int), stream);

        int eblocks = (N_EDGES + 255) / 256;
        hist_kernel<<<eblocks, 256, 0, stream>>>(dst, cursor);
        scan_kernel<<<N_SCAN_BLOCKS, SCAN_B, 0, stream>>>(cursor, desc,
                                                          offsets, cursor);
        fill_kernel<<<eblocks, 256, 0, stream>>>(dst, cursor, edge_ids);

        int gblocks = (N_NODES + TILE_N - 1) / TILE_N;  // 1563
        fused_tile<<<gblocks, 256, 0, stream>>>(h, e_h, offsets, edge_ids,
                                                norm, W, b, out);
    } else {
        const size_t s_bytes = (size_t)N_NODES * D * sizeof(float);
        float* S = (ws_size >= s_bytes) ? (float*)d_ws : out;
        hipMemsetAsync(S, 0, s_bytes, stream);
        int scatter_blocks = (N_EDGES * 32 + 255) / 256;
        scatter_kernel<<<scatter_blocks, 256, 0, stream>>>(e_h, dst, S);
        int gemm_blocks = (N_NODES + TILE_N - 1) / TILE_N;
        gemm_kernel<<<gemm_blocks, 256, 0, stream>>>(h, S, norm, W, b, out);
    }
}

// Round 3
// 172.046 us; speedup vs baseline: 1.1243x; 1.1243x over previous
//
#include <hip/hip_runtime.h>

#define N_NODES 50000
#define N_EDGES 600000
#define D 128
#define TILE_N 32
#define SCAN_B 1024
#define N_SCAN_BLOCKS ((N_NODES + SCAN_B - 1) / SCAN_B)   // 49

typedef float f4 __attribute__((ext_vector_type(4)));

// ===========================================================================
// R3 structure: 6 dispatches.
//   memset(cursor+desc) -> hist -> single-kernel scan (decoupled aggregates)
//   -> fill -> agg (high-occupancy gather, shfl-broadcast ids) -> gemm.
//   A[n] = h[n] .* segsum(e_h, dst)[n];  out = (A @ W^T + b) * norm
// ===========================================================================

__global__ __launch_bounds__(256) void hist_kernel(
    const int* __restrict__ dst, int* __restrict__ cnt)
{
    int e = blockIdx.x * 256 + threadIdx.x;
    if (e < N_EDGES) atomicAdd(&cnt[dst[e]], 1);
}

// ---------------------------------------------------------------------------
// One-kernel exclusive scan over cnt[N_NODES], 49 blocks x 1024.
// Block scan in LDS/shuffle; publish aggregate with device-scope release
// (bit63 = ready); one wave waits on all PREDECESSOR aggregates (49 blocks
// co-resident on 256 CUs, predecessor-only wait => deadlock-free).
// Verified correct in R2.
// ---------------------------------------------------------------------------
__global__ __launch_bounds__(SCAN_B) void scan_kernel(
    const int* __restrict__ cnt, unsigned long long* __restrict__ desc,
    int* __restrict__ offsets, int* __restrict__ cursor)
{
    const int t  = threadIdx.x;
    const int bx = blockIdx.x;
    const int i  = bx * SCAN_B + t;
    const int v  = (i < N_NODES) ? cnt[i] : 0;

    const int lane = t & 63;
    const int w    = t >> 6;                 // 16 waves
    int incl = v;
#pragma unroll
    for (int s = 1; s < 64; s <<= 1) {
        int u = __shfl_up(incl, s, 64);
        if (lane >= s) incl += u;
    }
    __shared__ int wsum[SCAN_B / 64];
    if (lane == 63) wsum[w] = incl;
    __syncthreads();
    if (t < SCAN_B / 64) {
        int x = wsum[t];
#pragma unroll
        for (int s = 1; s < SCAN_B / 64; s <<= 1) {
            int u = __shfl_up(x, s, SCAN_B / 64);
            if (t >= s) x += u;
        }
        wsum[t] = x;                         // inclusive per-wave prefix
    }
    __syncthreads();
    const int block_total   = wsum[SCAN_B / 64 - 1];
    const int excl_in_block = (w ? wsum[w - 1] : 0) + (incl - v);

    if (t == 0)
        __hip_atomic_store(&desc[bx],
            (unsigned long long)(unsigned)block_total | (1ull << 63),
            __ATOMIC_RELEASE, __HIP_MEMORY_SCOPE_AGENT);

    __shared__ int base_sh;
    if (t < 64) {
        int pred = 0;
        if (t < bx) {                        // bx <= 48 < 64: one wave covers all
            unsigned long long e;
            do {
                e = __hip_atomic_load(&desc[t], __ATOMIC_ACQUIRE,
                                      __HIP_MEMORY_SCOPE_AGENT);
            } while (!(e >> 63));
            pred = (int)(unsigned)e;
        }
#pragma unroll
        for (int s = 32; s > 0; s >>= 1) pred += __shfl_down(pred, s, 64);
        if (t == 0) base_sh = pred;
    }
    __syncthreads();

    const int excl = base_sh + excl_in_block;
    if (i < N_NODES) { offsets[i] = excl; cursor[i] = excl; }
    if (i == N_NODES - 1) offsets[N_NODES] = excl + v;   // == N_EDGES
}

__global__ __launch_bounds__(256) void fill_kernel(
    const int* __restrict__ dst, int* __restrict__ cursor,
    int* __restrict__ edge_ids)
{
    int e = blockIdx.x * 256 + threadIdx.x;
    if (e < N_EDGES) {
        int pos = atomicAdd(&cursor[dst[e]], 1);
        edge_ids[pos] = e;
    }
}

// ---------------------------------------------------------------------------
// Aggregate: A[n] = h[n] .* sum(e_h rows). 32 lanes/node, one float4/lane.
//
// R3 change: edge ids loaded COALESCED (one 32-wide load per 32 edges) and
// distributed via __shfl broadcast, instead of every lane loading the same
// edge_ids[i] scalar. Halves VMEM instruction count in the hot loop (was
// 1 id-load + 1 row-load per edge; now 1/32 + 1). Row loads stay 4-deep,
// nontemporal (e_h is a read-once 307MB stream; keep it from thrashing L2).
// ---------------------------------------------------------------------------
__global__ __launch_bounds__(256) void agg_kernel(
    const float* __restrict__ h, const float* __restrict__ e_h,
    const int* __restrict__ offsets, const int* __restrict__ edge_ids,
    float* __restrict__ A)
{
    int gid  = blockIdx.x * 256 + threadIdx.x;
    int node = gid >> 5;
    int lane = gid & 31;
    if (node >= N_NODES) return;

    const int beg = offsets[node];
    const int end = offsets[node + 1];
    const int fo  = lane << 2;

    f4 acc = (f4){0.f, 0.f, 0.f, 0.f};

    for (int c = beg; c < end; c += 32) {
        const int rem = end - c;
        const int cap = rem < 32 ? rem : 32;
        int myid = (lane < cap) ? edge_ids[c + lane] : 0;   // coalesced

        int j = 0;
        const int cap4 = cap & ~3;
        for (; j < cap4; j += 4) {
            int id0 = __shfl(myid, j + 0, 32);
            int id1 = __shfl(myid, j + 1, 32);
            int id2 = __shfl(myid, j + 2, 32);
            int id3 = __shfl(myid, j + 3, 32);
            f4 v0 = __builtin_nontemporal_load((const f4*)(e_h + (size_t)id0 * D + fo));
            f4 v1 = __builtin_nontemporal_load((const f4*)(e_h + (size_t)id1 * D + fo));
            f4 v2 = __builtin_nontemporal_load((const f4*)(e_h + (size_t)id2 * D + fo));
            f4 v3 = __builtin_nontemporal_load((const f4*)(e_h + (size_t)id3 * D + fo));
            acc += (v0 + v1) + (v2 + v3);
        }
        for (; j < cap; ++j) {
            int id = __shfl(myid, j, 32);
            f4 v = __builtin_nontemporal_load((const f4*)(e_h + (size_t)id * D + fo));
            acc += v;
        }
    }

    f4 hv = *(const f4*)(h + (size_t)node * D + fo);
    acc *= hv;
    *(f4*)(A + (size_t)node * D + fo) = acc;
}

// ---------------------------------------------------------------------------
// GEMM: out = (A @ W^T + b) * norm.  32 nodes x 128 cols / block.
// W granule-swizzled in LDS (64KB) + A tile (16KB) -> 2 blocks/CU (compute
// phase; fine). Per thread 4 nodes x 4 cols.
// ---------------------------------------------------------------------------
__global__ __launch_bounds__(256, 2) void gemm_from_A(
    const float* __restrict__ A, const float* __restrict__ norm,
    const float* __restrict__ W, const float* __restrict__ b,
    float* __restrict__ out)
{
    __shared__ float Wl[D * D];
    __shared__ float Al[TILE_N * D];
    const int tid = threadIdx.x;
    const int n0  = blockIdx.x * TILE_N;

    for (int it = 0; it < 16; ++it) {
        int group = it * 256 + tid;
        int c  = group >> 5;
        int kg = group & 31;
        float4 wv = *(const float4*)(W + (size_t)c * D + (kg << 2));
        int g = (kg + c) & 31;
        *(float4*)(Wl + c * D + (g << 2)) = wv;
    }
    for (int it = 0; it < 4; ++it) {
        int group = it * 256 + tid;
        int nl = group >> 5;
        int f  = (group & 31) << 2;
        int n  = n0 + nl;
        float4 a = make_float4(0.f, 0.f, 0.f, 0.f);
        if (n < N_NODES) a = *(const float4*)(A + (size_t)n * D + f);
        *(float4*)(Al + nl * D + f) = a;
    }
    __syncthreads();

    const int cg = tid & 31;
    const int ng = tid >> 5;
    float facc[4][4];
#pragma unroll
    for (int i = 0; i < 4; ++i)
#pragma unroll
        for (int j = 0; j < 4; ++j) facc[i][j] = 0.f;

#pragma unroll 4
    for (int kc = 0; kc < 32; ++kc) {
        float4 a[4];
#pragma unroll
        for (int i = 0; i < 4; ++i)
            a[i] = *(const float4*)(Al + (ng * 4 + i) * D + (kc << 2));
        float4 w[4];
#pragma unroll
        for (int j = 0; j < 4; ++j) {
            int c = cg + 32 * j;
            int g = (kc + c) & 31;
            w[j] = *(const float4*)(Wl + c * D + (g << 2));
        }
#pragma unroll
        for (int i = 0; i < 4; ++i)
#pragma unroll
            for (int j = 0; j < 4; ++j)
                facc[i][j] += a[i].x * w[j].x + a[i].y * w[j].y +
                              a[i].z * w[j].z + a[i].w * w[j].w;
    }
    float bias[4];
#pragma unroll
    for (int j = 0; j < 4; ++j) bias[j] = b[cg + 32 * j];
#pragma unroll
    for (int i = 0; i < 4; ++i) {
        int n = n0 + ng * 4 + i;
        if (n >= N_NODES) break;
        float nv = norm[n];
#pragma unroll
        for (int j = 0; j < 4; ++j)
            out[(size_t)n * D + cg + 32 * j] = (facc[i][j] + bias[j]) * nv;
    }
}

// ===========================================================================
// Fallback (tiny ws): float-atomic scatter + fused gemm
// ===========================================================================
__global__ __launch_bounds__(256) void scatter_kernel(
    const float* __restrict__ e_h, const int* __restrict__ dst,
    float* __restrict__ S)
{
    long long idx = (long long)blockIdx.x * 256 + threadIdx.x;
    int edge = (int)(idx >> 5);
    if (edge >= N_EDGES) return;
    int f = ((int)idx & 31) << 2;
    const float4 v = *(const float4*)(e_h + (size_t)edge * D + f);
    float* p = S + (size_t)dst[edge] * D + f;
    atomicAdd(p + 0, v.x);
    atomicAdd(p + 1, v.y);
    atomicAdd(p + 2, v.z);
    atomicAdd(p + 3, v.w);
}

__global__ __launch_bounds__(256, 2) void gemm_kernel(
    const float* __restrict__ h, const float* __restrict__ S,
    const float* __restrict__ norm, const float* __restrict__ W,
    const float* __restrict__ b, float* __restrict__ out)
{
    __shared__ float Wl[D * D];
    __shared__ float Al[TILE_N * D];
    const int tid = threadIdx.x;
    const int n0  = blockIdx.x * TILE_N;

    for (int it = 0; it < 16; ++it) {
        int group = it * 256 + tid;
        int c  = group >> 5;
        int kg = group & 31;
        float4 wv = *(const float4*)(W + (size_t)c * D + (kg << 2));
        int g = (kg + c) & 31;
        *(float4*)(Wl + c * D + (g << 2)) = wv;
    }
    for (int it = 0; it < 4; ++it) {
        int group = it * 256 + tid;
        int nl = group >> 5;
        int f  = (group & 31) << 2;
        int n  = n0 + nl;
        float4 a = make_float4(0.f, 0.f, 0.f, 0.f);
        if (n < N_NODES) {
            float4 hv = *(const float4*)(h + (size_t)n * D + f);
            float4 sv = *(const float4*)(S + (size_t)n * D + f);
            a = make_float4(hv.x * sv.x, hv.y * sv.y, hv.z * sv.z, hv.w * sv.w);
        }
        *(float4*)(Al + nl * D + f) = a;
    }
    __syncthreads();

    const int cg = tid & 31;
    const int ng = tid >> 5;
    float facc[4][4];
#pragma unroll
    for (int i = 0; i < 4; ++i)
#pragma unroll
        for (int j = 0; j < 4; ++j) facc[i][j] = 0.f;

#pragma unroll 4
    for (int kc = 0; kc < 32; ++kc) {
        float4 a[4];
#pragma unroll
        for (int i = 0; i < 4; ++i)
            a[i] = *(const float4*)(Al + (ng * 4 + i) * D + (kc << 2));
        float4 w[4];
#pragma unroll
        for (int j = 0; j < 4; ++j) {
            int c = cg + 32 * j;
            int g = (kc + c) & 31;
            w[j] = *(const float4*)(Wl + c * D + (g << 2));
        }
#pragma unroll
        for (int i = 0; i < 4; ++i)
#pragma unroll
            for (int j = 0; j < 4; ++j)
                facc[i][j] += a[i].x * w[j].x + a[i].y * w[j].y +
                              a[i].z * w[j].z + a[i].w * w[j].w;
    }
    float bias[4];
#pragma unroll
    for (int j = 0; j < 4; ++j) bias[j] = b[cg + 32 * j];
#pragma unroll
    for (int i = 0; i < 4; ++i) {
        int n = n0 + ng * 4 + i;
        if (n >= N_NODES) break;
        float nv = norm[n];
#pragma unroll
        for (int j = 0; j < 4; ++j)
            out[(size_t)n * D + cg + 32 * j] = (facc[i][j] + bias[j]) * nv;
    }
}

// ===========================================================================
extern "C" void kernel_launch(void* const* d_in, const int* in_sizes, int n_in,
                              void* d_out, int out_size, void* d_ws, size_t ws_size,
                              hipStream_t stream) {
    const float* h    = (const float*)d_in[0];
    const float* e_h  = (const float*)d_in[1];
    const float* norm = (const float*)d_in[2];
    const int*   dst  = (const int*)d_in[3];
    const float* W    = (const float*)d_in[4];
    const float* b    = (const float*)d_in[5];
    float* out = (float*)d_out;

    // ws layout: cursor[N] | desc[64 u64] | offsets[N+1] | edge_ids[E] | A[N*D]
    const size_t ints_needed = (size_t)N_NODES + 128 + (N_NODES + 1) + N_EDGES;
    const size_t full_bytes  = ints_needed * sizeof(int)
                             + (size_t)N_NODES * D * sizeof(float);

    if (ws_size >= full_bytes) {
        int* cursor   = (int*)d_ws;
        unsigned long long* desc = (unsigned long long*)(cursor + N_NODES);
        int* offsets  = cursor + N_NODES + 128;
        int* edge_ids = offsets + N_NODES + 1;
        float* A      = (float*)(edge_ids + N_EDGES);

        // zero counts + scan descriptors in one memset
        hipMemsetAsync(cursor, 0, ((size_t)N_NODES + 128) * sizeof(int), stream);

        int eblocks = (N_EDGES + 255) / 256;
        hist_kernel<<<eblocks, 256, 0, stream>>>(dst, cursor);
        scan_kernel<<<N_SCAN_BLOCKS, SCAN_B, 0, stream>>>(cursor, desc,
                                                          offsets, cursor);
        fill_kernel<<<eblocks, 256, 0, stream>>>(dst, cursor, edge_ids);

        int ablocks = ((N_NODES * 32) + 255) / 256;   // 6250
        agg_kernel<<<ablocks, 256, 0, stream>>>(h, e_h, offsets, edge_ids, A);

        int gblocks = (N_NODES + TILE_N - 1) / TILE_N;  // 1563
        gemm_from_A<<<gblocks, 256, 0, stream>>>(A, norm, W, b, out);
    } else {
        const size_t s_bytes = (size_t)N_NODES * D * sizeof(float);
        float* S = (ws_size >= s_bytes) ? (float*)d_ws : out;
        hipMemsetAsync(S, 0, s_bytes, stream);
        int scatter_blocks = (N_EDGES * 32 + 255) / 256;
        scatter_kernel<<<scatter_blocks, 256, 0, stream>>>(e_h, dst, S);
        int gemm_blocks = (N_NODES + TILE_N - 1) / TILE_N;
        gemm_kernel<<<gemm_blocks, 256, 0, stream>>>(h, S, norm, W, b, out);
    }
}